// Round 8
// baseline (115.404 us; speedup 1.0000x reference)
//
#include <hip/hip_runtime.h>
#include <cstdint>
#include <cstddef>

// ---------------------------------------------------------------------------
// ChannelWiseCrossAttention: B=4, C=64, H=W=64, N=4096
// Workspace layouts are MFMA-fragment-major (wave-contiguous loads):
//   Q,K per (b, 32-row tile): [kc(4)][hi(2)][il(32)][e(8)]  (2048 elems)
//     element (row il, c = kc*16+hi*8+e)
//   V  per (b, 32-col tile):  [kcs(4)][hi(2)][c(64)][e(4)]  (2048 elems)
//     element (c, j = kcs*8+hi*4+e)
// attn: 256 blocks x 8 waves. Block = (b, 256 Q-rows, j-quarter); wave owns
//   its own 32 Q-rows (no cross-wave combine). K/V tiles staged in
//   double-buffered LDS shared by all 8 waves (L2 traffic 64 MB total).
//   S^T = K Q^T (mfma_f32_32x32x16_bf16), p = exp2(S' - SHIFT) in-register,
//   O^T += V P^T (32x32x8; S^T C/D regs 4g..4g+3 are the B-frag).
//   fp32 partial (O,l) per j-quarter -> ws; epilogue sums 4, out=g*O/l+x1.
// ---------------------------------------------------------------------------

typedef __bf16 bf16x4 __attribute__((ext_vector_type(4)));
typedef __bf16 bf16x8 __attribute__((ext_vector_type(8)));
typedef float  f32x4  __attribute__((ext_vector_type(4)));
typedef float  f32x16 __attribute__((ext_vector_type(16)));
typedef short  s16x4  __attribute__((ext_vector_type(4)));

constexpr int C = 64;
constexpr int N = 4096;
constexpr float LOG2E = 1.44269504088896340736f;
constexpr float EXPSHIFT = 48.0f * 1.44269504088896340736f;  // ln-domain 48

static __device__ __forceinline__ f32x4 mfma16(bf16x8 a, bf16x8 b, f32x4 c) {
    return __builtin_amdgcn_mfma_f32_16x16x32_bf16(a, b, c, 0, 0, 0);
}
static __device__ __forceinline__ f32x16 mfma32(bf16x8 a, bf16x8 b, f32x16 c) {
    return __builtin_amdgcn_mfma_f32_32x32x16_bf16(a, b, c, 0, 0, 0);
}
// 32x32x8 bf16 (A/B = 4 bf16, k = 4*hi + j). Native if available, else
// zero-padded 32x32x16 (logical k at slot j in both operands).
static __device__ __forceinline__ f32x16 pv_mfma(bf16x4 a, bf16x4 b, f32x16 c) {
#if __has_builtin(__builtin_amdgcn_mfma_f32_32x32x8bf16_1k)
    union U { bf16x4 h; s16x4 s; };
    U ua; ua.h = a;
    U ub; ub.h = b;
    return __builtin_amdgcn_mfma_f32_32x32x8bf16_1k(ua.s, ub.s, c, 0, 0, 0);
#else
    const __bf16 z = (__bf16)0.0f;
    bf16x8 a8 = {a[0], a[1], a[2], a[3], z, z, z, z};
    bf16x8 b8 = {b[0], b[1], b[2], b[3], z, z, z, z};
    return __builtin_amdgcn_mfma_f32_32x32x16_bf16(a8, b8, c, 0, 0, 0);
#endif
}
static __device__ __forceinline__ float fast_exp2(float x) {
#if __has_builtin(__builtin_amdgcn_exp2f)
    return __builtin_amdgcn_exp2f(x);
#else
    return exp2f(x);
#endif
}

// ---------------------------------------------------------------------------
// QKV conv. grid = 256 x 256 thr. MFMA compute as in round 5, but results
// round-trip a padded LDS transpose so ALL global stores are 16B contiguous.
// ---------------------------------------------------------------------------
__global__ __launch_bounds__(256) void qkv_kernel(
    const float* __restrict__ x1, const float* __restrict__ x2,
    const float* __restrict__ wq, const float* __restrict__ bq,
    const float* __restrict__ wk, const float* __restrict__ bk,
    const float* __restrict__ wv, const float* __restrict__ bv,
    __bf16* __restrict__ qo, __bf16* __restrict__ ko, __bf16* __restrict__ vo)
{
    __shared__ __bf16 wl[3][64][72];
    __shared__ __bf16 tq[64][72];   // [pixel][o], pad 72 (16B-aligned rows)
    __shared__ __bf16 tk[64][72];

    const int tid   = threadIdx.x;
    const int b     = blockIdx.x >> 6;
    const int nbase = (blockIdx.x & 63) * 64;

    {
        const float* wp[3] = {wq, wk, wv};
#pragma unroll
        for (int m = 0; m < 3; ++m)
#pragma unroll
            for (int i = 0; i < 4; ++i) {
                int idx = i * 256 + tid;
                int row = idx >> 4, c4 = (idx & 15) * 4;
                float4 a = *(const float4*)(wp[m] + row * 64 + c4);
                bf16x4 h = {(__bf16)a.x, (__bf16)a.y, (__bf16)a.z, (__bf16)a.w};
                *(bf16x4*)&wl[m][row][c4] = h;
            }
    }
    __syncthreads();

    const int wave = tid >> 6, lane = tid & 63;
    const int l = lane & 15, qd = lane >> 4;
    const int p = nbase + wave * 16 + l;          // pixel (A col)

    const float* x1b = x1 + (size_t)b * C * N + p;
    const float* x2b = x2 + (size_t)b * C * N + p;
    bf16x8 ax1[2], ax2[2];
#pragma unroll
    for (int ks = 0; ks < 2; ++ks)
#pragma unroll
        for (int j = 0; j < 8; ++j) {
            int c = ks * 32 + qd * 8 + j;
            ax1[ks][j] = (__bf16)x1b[(size_t)c * N];
            ax2[ks][j] = (__bf16)x2b[(size_t)c * N];
        }

    // ---- Q, K: D[pixel][o] -> tq/tk ----
#pragma unroll
    for (int ot = 0; ot < 4; ++ot) {
        const float bqv = bq[ot * 16 + l];
        const float bkv = bk[ot * 16 + l];
        f32x4 aq = {bqv, bqv, bqv, bqv};
        f32x4 ak = {bkv, bkv, bkv, bkv};
#pragma unroll
        for (int ks = 0; ks < 2; ++ks) {
            bf16x8 bwq = *(const bf16x8*)&wl[0][ot * 16 + l][ks * 32 + qd * 8];
            bf16x8 bwk = *(const bf16x8*)&wl[1][ot * 16 + l][ks * 32 + qd * 8];
            aq = mfma16(ax1[ks], bwq, aq);
            ak = mfma16(ax2[ks], bwk, ak);
        }
#pragma unroll
        for (int r = 0; r < 4; ++r) {
            int px = wave * 16 + qd * 4 + r;
            tq[px][ot * 16 + l] = (__bf16)(aq[r] * LOG2E);
            tk[px][ot * 16 + l] = (__bf16)ak[r];
        }
    }
    __syncthreads();

    // ---- drain Q, K: frag-major 16B contiguous stores ----
    {
        const int tile = tid >> 7, t7 = tid & 127;
        const int kc = t7 >> 5, h2 = (t7 >> 4) & 1, ilp = (t7 & 15) * 2;
        const size_t tb = ((size_t)b * 128 + (nbase >> 5) + tile) * 2048;
        const size_t off = tb + kc * 512 + h2 * 256 + ilp * 8;
        bf16x8 ra = *(const bf16x8*)&tq[tile * 32 + ilp][kc * 16 + h2 * 8];
        bf16x8 rb = *(const bf16x8*)&tq[tile * 32 + ilp + 1][kc * 16 + h2 * 8];
        *(bf16x8*)&qo[off]     = ra;
        *(bf16x8*)&qo[off + 8] = rb;
        ra = *(const bf16x8*)&tk[tile * 32 + ilp][kc * 16 + h2 * 8];
        rb = *(const bf16x8*)&tk[tile * 32 + ilp + 1][kc * 16 + h2 * 8];
        *(bf16x8*)&ko[off]     = ra;
        *(bf16x8*)&ko[off + 8] = rb;
    }
    __syncthreads();

    // ---- V: D[o][pixel] -> tq (reuse) as [pixel][o] ----
#pragma unroll
    for (int ct = 0; ct < 4; ++ct) {
        f32x4 av;
#pragma unroll
        for (int r = 0; r < 4; ++r) av[r] = bv[ct * 16 + qd * 4 + r];
#pragma unroll
        for (int ks = 0; ks < 2; ++ks) {
            bf16x8 awv = *(const bf16x8*)&wl[2][ct * 16 + l][ks * 32 + qd * 8];
            av = mfma16(awv, ax2[ks], av);
        }
        bf16x4 pk = {(__bf16)av[0], (__bf16)av[1], (__bf16)av[2], (__bf16)av[3]};
        *(bf16x4*)&tq[wave * 16 + l][ct * 16 + qd * 4] = pk;
    }
    __syncthreads();

    // ---- drain V: [kcs][vhi][c][e4], 16B contiguous stores ----
    {
        const int tile = tid >> 7, t7 = tid & 127;
        const int g = t7 >> 5, vh = (t7 >> 4) & 1, c0 = (t7 & 15) * 4;
        const int pxb = tile * 32 + g * 8 + vh * 4;
        bf16x4 e0 = *(const bf16x4*)&tq[pxb + 0][c0];
        bf16x4 e1 = *(const bf16x4*)&tq[pxb + 1][c0];
        bf16x4 e2 = *(const bf16x4*)&tq[pxb + 2][c0];
        bf16x4 e3 = *(const bf16x4*)&tq[pxb + 3][c0];
        bf16x8 o1, o2;
        o1[0]=e0[0]; o1[1]=e1[0]; o1[2]=e2[0]; o1[3]=e3[0];
        o1[4]=e0[1]; o1[5]=e1[1]; o1[6]=e2[1]; o1[7]=e3[1];
        o2[0]=e0[2]; o2[1]=e1[2]; o2[2]=e2[2]; o2[3]=e3[2];
        o2[4]=e0[3]; o2[5]=e1[3]; o2[6]=e2[3]; o2[7]=e3[3];
        const size_t tb = ((size_t)b * 128 + (nbase >> 5) + tile) * 2048;
        const size_t off = tb + g * 512 + vh * 256 + c0 * 4;
        *(bf16x8*)&vo[off]     = o1;
        *(bf16x8*)&vo[off + 8] = o2;
    }
}

// ---------------------------------------------------------------------------
// Attention partials. grid = 256 blocks x 512 thr (8 waves).
// Block = (b, qt: 256 Q-rows, jq: quarter of j). Wave w owns Q-tile qt*8+w
// (32 rows). Per 32-j tile: K (4KB) + V (4KB) staged into dbuf LDS by all
// 512 threads (16B each), consumed by all 8 waves. One barrier per tile.
// XCD swizzle: bid&7 = (b<<1)|(qt&1) so a (b,qt)'s 4 jq-partials stay on
// one XCD's L2 for the epilogue.
// 32x32x16: A/B 8 elems k=(lane>>5)*8+j; C/D row=(r&3)+8*(r>>2)+4*hi, col=il.
// ---------------------------------------------------------------------------
__global__ __launch_bounds__(512, 2) void attn_kernel(
    const __bf16* __restrict__ qg, const __bf16* __restrict__ kg,
    const __bf16* __restrict__ vg,
    float* __restrict__ partO, float* __restrict__ partL)
{
    __shared__ __bf16 stage[2][4096];   // [buf][K 2048 | V 2048], 16 KB

    const int bid   = blockIdx.x;
    const int xcd   = bid & 7;
    const int b     = xcd >> 1;
    const int qlow  = xcd & 1;
    const int hi5   = bid >> 3;          // 0..31
    const int qhigh = hi5 >> 2;          // 0..7
    const int jq    = hi5 & 3;           // j-quarter
    const int qt    = qhigh * 2 + qlow;  // 0..15

    const int tid  = threadIdx.x;
    const int wave = tid >> 6, lane = tid & 63;
    const int il = lane & 31, hi = lane >> 5;

    // Q B-frags: wave's own 32-row tile, 1 KB contiguous per load
    const __bf16* qtile = qg + ((size_t)b * 128 + qt * 8 + wave) * 2048;
    bf16x8 bqf[4];
#pragma unroll
    for (int kc = 0; kc < 4; ++kc)
        bqf[kc] = *(const bf16x8*)(qtile + kc * 512 + lane * 8);

    // K/V j-range: 32 tiles starting at jq*32
    const __bf16* kbase = kg + ((size_t)b * 128 + jq * 32) * 2048;
    const __bf16* vbase = vg + ((size_t)b * 128 + jq * 32) * 2048;
    const __bf16* mysrc = (tid < 256 ? kbase : vbase) + (size_t)(tid & 255) * 8;

    f32x16 accO[2];
#pragma unroll
    for (int ct = 0; ct < 2; ++ct)
#pragma unroll
        for (int r = 0; r < 16; ++r) accO[ct][r] = 0.f;
    float lsum = 0.f;

    // stage tile 0
    {
        bf16x8 v = *(const bf16x8*)mysrc;
        *(bf16x8*)&stage[0][tid * 8] = v;
    }
    __syncthreads();

    for (int t = 0; t < 32; ++t) {
        const int buf = t & 1;
        // prefetch tile t+1 from global (latency covered by compute below)
        bf16x8 pre;
        if (t < 31) pre = *(const bf16x8*)(mysrc + (size_t)(t + 1) * 2048);

        // fragments from LDS
        bf16x8 akf[4];
#pragma unroll
        for (int kc = 0; kc < 4; ++kc)
            akf[kc] = *(const bf16x8*)&stage[buf][kc * 512 + lane * 8];
        bf16x4 avf[2][4];
#pragma unroll
        for (int ct = 0; ct < 2; ++ct)
#pragma unroll
            for (int g = 0; g < 4; ++g)
                avf[ct][g] = *(const bf16x4*)&stage[buf][2048 + g * 512 + hi * 256 + ct * 128 + il * 4];

        // S^T = K Q^T
        f32x16 st;
#pragma unroll
        for (int r = 0; r < 16; ++r) st[r] = 0.f;
#pragma unroll
        for (int kc = 0; kc < 4; ++kc) st = mfma32(akf[kc], bqf[kc], st);

        // p = exp2(S' - SHIFT); regs 4g..4g+3 = B-frag of PV k-chunk g
        bf16x4 bp[4];
#pragma unroll
        for (int r = 0; r < 16; ++r) {
            float pv = fast_exp2(st[r] - EXPSHIFT);
            lsum += pv;
            bp[r >> 2][r & 3] = (__bf16)pv;
        }

        // O^T += V P^T
#pragma unroll
        for (int ct = 0; ct < 2; ++ct)
#pragma unroll
            for (int g = 0; g < 4; ++g)
                accO[ct] = pv_mfma(avf[ct][g], bp[g], accO[ct]);

        // write prefetched tile into the other buffer (safe: idle this iter)
        if (t < 31) *(bf16x8*)&stage[buf ^ 1][tid * 8] = pre;
        __syncthreads();
    }

    // per-lane lsum -> per-Q-row total (combine hi halves)
    lsum += __shfl_xor(lsum, 32);

    // ---- store fp32 partials: [(b*16+qt)*4+jq][c 64][i 256] ----
    float* po = partO + (((size_t)(b * 16 + qt) * 4 + jq) * 64) * 256;
#pragma unroll
    for (int ct = 0; ct < 2; ++ct)
#pragma unroll
        for (int r = 0; r < 16; ++r) {
            int c = ct * 32 + (r & 3) + 8 * (r >> 2) + 4 * hi;
            po[(size_t)c * 256 + wave * 32 + il] = accO[ct][r];
        }
    if (hi == 0)
        partL[((size_t)(b * 16 + qt) * 4 + jq) * 256 + wave * 32 + il] = lsum;
}

// ---------------------------------------------------------------------------
// Epilogue: sum 4 jq-partials, out = gamma*O/l + x1.
// grid = 256 blocks x 256 thr; bid&7 matches attn's swizzle (L2-local reads).
// Block = (b, qt, i-quarter): 64 c x 64 i.
// ---------------------------------------------------------------------------
__global__ __launch_bounds__(256) void epilogue_kernel(
    const float* __restrict__ partO, const float* __restrict__ partL,
    const float* __restrict__ x1, const float* __restrict__ gamma,
    float* __restrict__ out)
{
    const int bid   = blockIdx.x;
    const int xcd   = bid & 7;
    const int b     = xcd >> 1;
    const int qlow  = xcd & 1;
    const int hi5   = bid >> 3;
    const int qhigh = hi5 >> 2;
    const int iq    = hi5 & 3;
    const int qt    = qhigh * 2 + qlow;

    const int tid = threadIdx.x;
    const int c   = tid >> 2;            // 0..63
    const int sub = tid & 3;             // i sub-block of 16
    const size_t pb = (size_t)(b * 16 + qt) * 4;
    const float g = gamma[0];

#pragma unroll
    for (int e4 = 0; e4 < 4; ++e4) {
        const int i0 = iq * 64 + sub * 16 + e4 * 4;
        f32x4 o = {0.f, 0.f, 0.f, 0.f};
        f32x4 lv = {0.f, 0.f, 0.f, 0.f};
#pragma unroll
        for (int j = 0; j < 4; ++j) {
            o  += *(const f32x4*)&partO[((pb + j) * 64 + c) * 256 + i0];
            lv += *(const f32x4*)&partL[(pb + j) * 256 + i0];
        }
        const size_t idx = ((size_t)b * C + c) * N + qt * 256 + i0;
        f32x4 xv = *(const f32x4*)(x1 + idx);
        f32x4 res;
#pragma unroll
        for (int e = 0; e < 4; ++e) res[e] = g * o[e] / lv[e] + xv[e];
        *(f32x4*)(out + idx) = res;
    }
}

// ---------------------------------------------------------------------------
extern "C" void kernel_launch(void* const* d_in, const int* in_sizes, int n_in,
                              void* d_out, int out_size, void* d_ws, size_t ws_size,
                              hipStream_t stream) {
    const float* x1    = (const float*)d_in[0];
    const float* x2    = (const float*)d_in[1];
    const float* wq    = (const float*)d_in[2];
    const float* bqv   = (const float*)d_in[3];
    const float* wk    = (const float*)d_in[4];
    const float* bkv   = (const float*)d_in[5];
    const float* wv    = (const float*)d_in[6];
    const float* bvv   = (const float*)d_in[7];
    const float* gamma = (const float*)d_in[8];
    float* out = (float*)d_out;

    __bf16* qws = (__bf16*)d_ws;                   // tiled Q, 2 MB
    __bf16* kws = qws + (size_t)4 * 128 * 2048;    // tiled K, 2 MB
    __bf16* vws = kws + (size_t)4 * 128 * 2048;    // tiled V, 2 MB
    float*  partO = (float*)(vws + (size_t)4 * 128 * 2048);   // 16.8 MB
    float*  partL = partO + (size_t)256 * 64 * 256;           // 256 KB

    qkv_kernel<<<256, 256, 0, stream>>>(x1, x2, wq, bqv, wk, bkv, wv, bvv, qws, kws, vws);
    attn_kernel<<<256, 512, 0, stream>>>(qws, kws, vws, partO, partL);
    epilogue_kernel<<<256, 256, 0, stream>>>(partO, partL, x1, gamma, out);
}

// Round 9
// 103.925 us; speedup vs baseline: 1.1105x; 1.1105x over previous
//
#include <hip/hip_runtime.h>
#include <cstdint>
#include <cstddef>

// ---------------------------------------------------------------------------
// ChannelWiseCrossAttention: B=4, C=64, H=W=64, N=4096
// Workspace layouts are MFMA-fragment-major (wave-contiguous loads):
//   Q,K per (b, 32-row tile): [kc(4)][hi(2)][il(32)][e(8)]  (2048 elems)
//     element (row il, c = kc*16+hi*8+e)
//   V  per (b, 32-col tile):  [kcs(4)][hi(2)][c(64)][e(4)]  (2048 elems)
//     element (c, j = kcs*8+hi*4+e)
// attn: 256 blocks x 8 waves; block = 64 Q-rows (2 subtiles); wave = 1/8 of j.
//   S^T = K Q^T (mfma_f32_32x32x16_bf16), p = exp2(S') UNSHIFTED (the
//   constant shift cancels in O/l; values stay in fp32/bf16 range),
//   O^T += V P^T (32x32x8; S^T C/D regs 4g..4g+3 are the B-frag).
//   8-wave partial (O,l) combine: 3-slot LDS tree + per-wave lsum array.
// ---------------------------------------------------------------------------

typedef __bf16 bf16x4 __attribute__((ext_vector_type(4)));
typedef __bf16 bf16x8 __attribute__((ext_vector_type(8)));
typedef float  f32x4  __attribute__((ext_vector_type(4)));
typedef float  f32x16 __attribute__((ext_vector_type(16)));
typedef short  s16x4  __attribute__((ext_vector_type(4)));

constexpr int C = 64;
constexpr int N = 4096;
constexpr float LOG2E = 1.44269504088896340736f;

static __device__ __forceinline__ f32x4 mfma16(bf16x8 a, bf16x8 b, f32x4 c) {
    return __builtin_amdgcn_mfma_f32_16x16x32_bf16(a, b, c, 0, 0, 0);
}
static __device__ __forceinline__ f32x16 mfma32(bf16x8 a, bf16x8 b, f32x16 c) {
    return __builtin_amdgcn_mfma_f32_32x32x16_bf16(a, b, c, 0, 0, 0);
}
// 32x32x8 bf16 (A/B = 4 bf16, k = 4*hi + j). Native if available, else
// zero-padded 32x32x16 (logical k at slot j in both operands).
static __device__ __forceinline__ f32x16 pv_mfma(bf16x4 a, bf16x4 b, f32x16 c) {
#if __has_builtin(__builtin_amdgcn_mfma_f32_32x32x8bf16_1k)
    union U { bf16x4 h; s16x4 s; };
    U ua; ua.h = a;
    U ub; ub.h = b;
    return __builtin_amdgcn_mfma_f32_32x32x8bf16_1k(ua.s, ub.s, c, 0, 0, 0);
#else
    const __bf16 z = (__bf16)0.0f;
    bf16x8 a8 = {a[0], a[1], a[2], a[3], z, z, z, z};
    bf16x8 b8 = {b[0], b[1], b[2], b[3], z, z, z, z};
    return __builtin_amdgcn_mfma_f32_32x32x16_bf16(a8, b8, c, 0, 0, 0);
#endif
}
static __device__ __forceinline__ float fast_exp2(float x) {
#if __has_builtin(__builtin_amdgcn_exp2f)
    return __builtin_amdgcn_exp2f(x);
#else
    return exp2f(x);
#endif
}

// ---------------------------------------------------------------------------
// QKV conv (R8's verified version: MFMA compute + padded LDS transpose so
// ALL global stores are 16B contiguous). grid = 256 x 256 thr.
// ---------------------------------------------------------------------------
__global__ __launch_bounds__(256) void qkv_kernel(
    const float* __restrict__ x1, const float* __restrict__ x2,
    const float* __restrict__ wq, const float* __restrict__ bq,
    const float* __restrict__ wk, const float* __restrict__ bk,
    const float* __restrict__ wv, const float* __restrict__ bv,
    __bf16* __restrict__ qo, __bf16* __restrict__ ko, __bf16* __restrict__ vo)
{
    __shared__ __bf16 wl[3][64][72];
    __shared__ __bf16 tq[64][72];   // [pixel][o], pad 72 (16B-aligned rows)
    __shared__ __bf16 tk[64][72];

    const int tid   = threadIdx.x;
    const int b     = blockIdx.x >> 6;
    const int nbase = (blockIdx.x & 63) * 64;

    {
        const float* wp[3] = {wq, wk, wv};
#pragma unroll
        for (int m = 0; m < 3; ++m)
#pragma unroll
            for (int i = 0; i < 4; ++i) {
                int idx = i * 256 + tid;
                int row = idx >> 4, c4 = (idx & 15) * 4;
                float4 a = *(const float4*)(wp[m] + row * 64 + c4);
                bf16x4 h = {(__bf16)a.x, (__bf16)a.y, (__bf16)a.z, (__bf16)a.w};
                *(bf16x4*)&wl[m][row][c4] = h;
            }
    }
    __syncthreads();

    const int wave = tid >> 6, lane = tid & 63;
    const int l = lane & 15, qd = lane >> 4;
    const int p = nbase + wave * 16 + l;          // pixel (A col)

    const float* x1b = x1 + (size_t)b * C * N + p;
    const float* x2b = x2 + (size_t)b * C * N + p;
    bf16x8 ax1[2], ax2[2];
#pragma unroll
    for (int ks = 0; ks < 2; ++ks)
#pragma unroll
        for (int j = 0; j < 8; ++j) {
            int c = ks * 32 + qd * 8 + j;
            ax1[ks][j] = (__bf16)x1b[(size_t)c * N];
            ax2[ks][j] = (__bf16)x2b[(size_t)c * N];
        }

    // ---- Q, K: D[pixel][o] -> tq/tk ----
#pragma unroll
    for (int ot = 0; ot < 4; ++ot) {
        const float bqv = bq[ot * 16 + l];
        const float bkv = bk[ot * 16 + l];
        f32x4 aq = {bqv, bqv, bqv, bqv};
        f32x4 ak = {bkv, bkv, bkv, bkv};
#pragma unroll
        for (int ks = 0; ks < 2; ++ks) {
            bf16x8 bwq = *(const bf16x8*)&wl[0][ot * 16 + l][ks * 32 + qd * 8];
            bf16x8 bwk = *(const bf16x8*)&wl[1][ot * 16 + l][ks * 32 + qd * 8];
            aq = mfma16(ax1[ks], bwq, aq);
            ak = mfma16(ax2[ks], bwk, ak);
        }
#pragma unroll
        for (int r = 0; r < 4; ++r) {
            int px = wave * 16 + qd * 4 + r;
            tq[px][ot * 16 + l] = (__bf16)(aq[r] * LOG2E);
            tk[px][ot * 16 + l] = (__bf16)ak[r];
        }
    }
    __syncthreads();

    // ---- drain Q, K: frag-major 16B contiguous stores ----
    {
        const int tile = tid >> 7, t7 = tid & 127;
        const int kc = t7 >> 5, h2 = (t7 >> 4) & 1, ilp = (t7 & 15) * 2;
        const size_t tb = ((size_t)b * 128 + (nbase >> 5) + tile) * 2048;
        const size_t off = tb + kc * 512 + h2 * 256 + ilp * 8;
        bf16x8 ra = *(const bf16x8*)&tq[tile * 32 + ilp][kc * 16 + h2 * 8];
        bf16x8 rb = *(const bf16x8*)&tq[tile * 32 + ilp + 1][kc * 16 + h2 * 8];
        *(bf16x8*)&qo[off]     = ra;
        *(bf16x8*)&qo[off + 8] = rb;
        ra = *(const bf16x8*)&tk[tile * 32 + ilp][kc * 16 + h2 * 8];
        rb = *(const bf16x8*)&tk[tile * 32 + ilp + 1][kc * 16 + h2 * 8];
        *(bf16x8*)&ko[off]     = ra;
        *(bf16x8*)&ko[off + 8] = rb;
    }
    __syncthreads();

    // ---- V: D[o][pixel] -> tq (reuse) as [pixel][o] ----
#pragma unroll
    for (int ct = 0; ct < 4; ++ct) {
        f32x4 av;
#pragma unroll
        for (int r = 0; r < 4; ++r) av[r] = bv[ct * 16 + qd * 4 + r];
#pragma unroll
        for (int ks = 0; ks < 2; ++ks) {
            bf16x8 awv = *(const bf16x8*)&wl[2][ct * 16 + l][ks * 32 + qd * 8];
            av = mfma16(awv, ax2[ks], av);
        }
        bf16x4 pk = {(__bf16)av[0], (__bf16)av[1], (__bf16)av[2], (__bf16)av[3]};
        *(bf16x4*)&tq[wave * 16 + l][ct * 16 + qd * 4] = pk;
    }
    __syncthreads();

    // ---- drain V: [kcs][vhi][c][e4], 16B contiguous stores ----
    {
        const int tile = tid >> 7, t7 = tid & 127;
        const int g = t7 >> 5, vh = (t7 >> 4) & 1, c0 = (t7 & 15) * 4;
        const int pxb = tile * 32 + g * 8 + vh * 4;
        bf16x4 e0 = *(const bf16x4*)&tq[pxb + 0][c0];
        bf16x4 e1 = *(const bf16x4*)&tq[pxb + 1][c0];
        bf16x4 e2 = *(const bf16x4*)&tq[pxb + 2][c0];
        bf16x4 e3 = *(const bf16x4*)&tq[pxb + 3][c0];
        bf16x8 o1, o2;
        o1[0]=e0[0]; o1[1]=e1[0]; o1[2]=e2[0]; o1[3]=e3[0];
        o1[4]=e0[1]; o1[5]=e1[1]; o1[6]=e2[1]; o1[7]=e3[1];
        o2[0]=e0[2]; o2[1]=e1[2]; o2[2]=e2[2]; o2[3]=e3[2];
        o2[4]=e0[3]; o2[5]=e1[3]; o2[6]=e2[3]; o2[7]=e3[3];
        const size_t tb = ((size_t)b * 128 + (nbase >> 5) + tile) * 2048;
        const size_t off = tb + g * 512 + vh * 256 + c0 * 4;
        *(bf16x8*)&vo[off]     = o1;
        *(bf16x8*)&vo[off + 8] = o2;
    }
}

// ---------------------------------------------------------------------------
// Attention. grid = 256 blocks x 512 thr. Block = (b, 64-row Q-tile = 2
// subtiles); wave w owns j-tiles [w*16, w*16+16). K double-buffered,
// V loaded early per tile. Unshifted exp2 (shift cancels in O/l).
// 32x32x16: A/B 8 elems k=(lane>>5)*8+j; C/D row=(r&3)+8*(r>>2)+4*hi, col=il.
// ---------------------------------------------------------------------------
__global__ __launch_bounds__(512, 2) void attn_kernel(
    const __bf16* __restrict__ qg, const __bf16* __restrict__ kg,
    const __bf16* __restrict__ vg, const float* __restrict__ x1,
    const float* __restrict__ gamma, float* __restrict__ out)
{
    __shared__ float lds_acc[3][64][64];   // 3 combine slots, 48 KB, [c][i]
    __shared__ float lds_l[8][64];         // per-wave lsum partials, [w][i]

    const int bid = blockIdx.x;
    const int xcd = bid & 7;
    const int b   = xcd >> 1;
    const int rt  = ((bid >> 3) << 1) | (xcd & 1);   // 0..63 (64-row tile)
    const int ibase = rt * 64;

    const int tid  = threadIdx.x;
    const int wave = tid >> 6, lane = tid & 63;
    const int il = lane & 31, hi = lane >> 5;

    const __bf16* qt = qg + ((size_t)b * 128 + rt * 2) * 2048;
    const __bf16* kt = kg + (size_t)b * 128 * 2048 + (size_t)(wave * 16) * 2048;
    const __bf16* vt = vg + (size_t)b * 128 * 2048 + (size_t)(wave * 16) * 2048;

    // Q B-frags for both 32-row subtiles: 1 KB contiguous per load
    bf16x8 bqf[2][4];
#pragma unroll
    for (int qs = 0; qs < 2; ++qs)
#pragma unroll
        for (int kc = 0; kc < 4; ++kc)
            bqf[qs][kc] = *(const bf16x8*)(qt + qs * 2048 + kc * 512 + lane * 8);

    f32x16 accO[4];   // [qs*2 + ct]
#pragma unroll
    for (int a = 0; a < 4; ++a)
#pragma unroll
        for (int r = 0; r < 16; ++r) accO[a][r] = 0.f;
    float lsum[2] = {0.f, 0.f};

    bf16x8 akf[2][4];   // K frags, double-buffered
    bf16x4 avf[2][4];   // V frags [ct][kcs]

#pragma unroll
    for (int kc = 0; kc < 4; ++kc)
        akf[0][kc] = *(const bf16x8*)(kt + kc * 512 + lane * 8);

#pragma unroll 2
    for (int t = 0; t < 16; ++t) {
        const int cur = t & 1;
        if (t < 15) {
#pragma unroll
            for (int kc = 0; kc < 4; ++kc)
                akf[cur ^ 1][kc] = *(const bf16x8*)(kt + (size_t)(t + 1) * 2048 + kc * 512 + lane * 8);
        }
#pragma unroll
        for (int ct = 0; ct < 2; ++ct)
#pragma unroll
            for (int kcs = 0; kcs < 4; ++kcs)
                avf[ct][kcs] = *(const bf16x4*)(vt + (size_t)t * 2048 + kcs * 512 + hi * 256 + ct * 128 + il * 4);

#pragma unroll
        for (int qs = 0; qs < 2; ++qs) {
            // S^T = K Q^T for this Q-subtile
            f32x16 st;
#pragma unroll
            for (int r = 0; r < 16; ++r) st[r] = 0.f;
#pragma unroll
            for (int kc = 0; kc < 4; ++kc) st = mfma32(akf[cur][kc], bqf[qs][kc], st);

            // p = exp2(S') (no shift; constant cancels in O/l).
            // regs 4g..4g+3 = B-frag of PV k-chunk g.
            bf16x4 bp[4];
            float lp0 = 0.f, lp1 = 0.f, lp2 = 0.f, lp3 = 0.f;
#pragma unroll
            for (int g = 0; g < 4; ++g) {
                float p0 = fast_exp2(st[g * 4 + 0]);
                float p1 = fast_exp2(st[g * 4 + 1]);
                float p2 = fast_exp2(st[g * 4 + 2]);
                float p3 = fast_exp2(st[g * 4 + 3]);
                lp0 += p0; lp1 += p1; lp2 += p2; lp3 += p3;
                bp[g][0] = (__bf16)p0; bp[g][1] = (__bf16)p1;
                bp[g][2] = (__bf16)p2; bp[g][3] = (__bf16)p3;
            }
            lsum[qs] += (lp0 + lp1) + (lp2 + lp3);

            // O^T += V P^T
#pragma unroll
            for (int ct = 0; ct < 2; ++ct)
#pragma unroll
                for (int g = 0; g < 4; ++g)
                    accO[qs * 2 + ct] = pv_mfma(avf[ct][g], bp[g], accO[qs * 2 + ct]);
        }
    }

    // per-lane lsum -> per-column(i) sum within wave (pair hi halves)
#pragma unroll
    for (int qs = 0; qs < 2; ++qs) lsum[qs] += __shfl_xor(lsum[qs], 32);
    if (hi == 0) {
        lds_l[wave][il]      = lsum[0];
        lds_l[wave][32 + il] = lsum[1];
    }

    // ---- cross-wave combine: 3-slot LDS tree ----
    // accO element (qs,ct,r) -> c = ct*32+(r&3)+8*(r>>2)+4*hi, i = qs*32+il
#define ACC_STORE(SLOT)                                                        \
    do {                                                                       \
        _Pragma("unroll")                                                      \
        for (int qs = 0; qs < 2; ++qs)                                         \
            _Pragma("unroll")                                                  \
            for (int ct = 0; ct < 2; ++ct)                                     \
                _Pragma("unroll")                                              \
                for (int r = 0; r < 16; ++r)                                   \
                    lds_acc[SLOT][ct * 32 + (r & 3) + 8 * (r >> 2) + 4 * hi][qs * 32 + il] = accO[qs * 2 + ct][r]; \
    } while (0)
#define ACC_LOAD(SLOT)                                                         \
    do {                                                                       \
        _Pragma("unroll")                                                      \
        for (int qs = 0; qs < 2; ++qs)                                         \
            _Pragma("unroll")                                                  \
            for (int ct = 0; ct < 2; ++ct)                                     \
                _Pragma("unroll")                                              \
                for (int r = 0; r < 16; ++r)                                   \
                    accO[qs * 2 + ct][r] += lds_acc[SLOT][ct * 32 + (r & 3) + 8 * (r >> 2) + 4 * hi][qs * 32 + il]; \
    } while (0)

    if (wave >= 5) ACC_STORE(wave - 5);                 // w5->0, w6->1, w7->2
    __syncthreads();
    if (wave >= 1 && wave <= 3) ACC_LOAD(wave - 1);     // w1+=w5, w2+=w6, w3+=w7
    __syncthreads();
    if (wave >= 2 && wave <= 4) ACC_STORE(wave - 2);    // w2->0, w3->1, w4->2
    __syncthreads();
    if (wave <= 1) ACC_LOAD(wave);                      // w0+=(w2+w6), w1+=(w3+w7)
    if (wave == 0) ACC_LOAD(2);                         // w0+=w4
    __syncthreads();
    if (wave == 1) ACC_STORE(0);                        // (w1+w5+w3+w7) -> s0
    __syncthreads();
    if (wave == 0) { ACC_LOAD(0); ACC_STORE(0); }       // total -> s0
    __syncthreads();
#undef ACC_STORE
#undef ACC_LOAD

    // ---- epilogue: out = gamma*O/l + x1 ----
    const float g = gamma[0];
    {
        const int c  = tid >> 3;           // 0..63
        const int i8 = (tid & 7) * 8;      // 0..56
        float lv[8];
#pragma unroll
        for (int e = 0; e < 8; ++e) {
            float s = 0.f;
#pragma unroll
            for (int w = 0; w < 8; ++w) s += lds_l[w][i8 + e];
            lv[e] = s;
        }
        const size_t idx = ((size_t)b * C + c) * N + ibase + i8;
        f32x4 o0 = *(const f32x4*)&lds_acc[0][c][i8];
        f32x4 o1 = *(const f32x4*)&lds_acc[0][c][i8 + 4];
        f32x4 x0 = *(const f32x4*)(x1 + idx);
        f32x4 x4 = *(const f32x4*)(x1 + idx + 4);
        f32x4 r0, r1;
#pragma unroll
        for (int e = 0; e < 4; ++e) {
            r0[e] = g * o0[e] / lv[e] + x0[e];
            r1[e] = g * o1[e] / lv[4 + e] + x4[e];
        }
        *(f32x4*)(out + idx) = r0;
        *(f32x4*)(out + idx + 4) = r1;
    }
}

// ---------------------------------------------------------------------------
extern "C" void kernel_launch(void* const* d_in, const int* in_sizes, int n_in,
                              void* d_out, int out_size, void* d_ws, size_t ws_size,
                              hipStream_t stream) {
    const float* x1    = (const float*)d_in[0];
    const float* x2    = (const float*)d_in[1];
    const float* wq    = (const float*)d_in[2];
    const float* bqv   = (const float*)d_in[3];
    const float* wk    = (const float*)d_in[4];
    const float* bkv   = (const float*)d_in[5];
    const float* wv    = (const float*)d_in[6];
    const float* bvv   = (const float*)d_in[7];
    const float* gamma = (const float*)d_in[8];
    float* out = (float*)d_out;

    __bf16* qws = (__bf16*)d_ws;                   // tiled Q, 2 MB
    __bf16* kws = qws + (size_t)4 * 128 * 2048;    // tiled K, 2 MB
    __bf16* vws = kws + (size_t)4 * 128 * 2048;    // tiled V, 2 MB

    qkv_kernel<<<256, 256, 0, stream>>>(x1, x2, wq, bqv, wk, bkv, wv, bvv, qws, kws, vws);
    attn_kernel<<<256, 512, 0, stream>>>(qws, kws, vws, x1, gamma, out);
}

// Round 10
// 103.654 us; speedup vs baseline: 1.1134x; 1.0026x over previous
//
#include <hip/hip_runtime.h>
#include <cstdint>
#include <cstddef>

// ---------------------------------------------------------------------------
// ChannelWiseCrossAttention: B=4, C=64, H=W=64, N=4096
// Workspace layouts are MFMA-fragment-major (wave-contiguous loads):
//   Q,K per (b, 32-row tile): [kc(4)][hi(2)][il(32)][e(8)]  (2048 elems)
//     element (row il, c = kc*16+hi*8+e)
//   V  per (b, 32-col tile):  [kcs(4)][hi(2)][c(64)][e(4)]  (2048 elems)
//     element (c, j = kcs*8+hi*4+e)
// qkv: ONE 768-block kernel; kind = bid>>8 in {Q,K,V}; block = 64 pixels of
//   one projection. 3x the waves/CU of the fused version (latency-bound fix).
// attn: 256 blocks x 8 waves; block = 64 Q-rows (2 subtiles); wave = 1/8 of j.
//   S^T = K Q^T (mfma_f32_32x32x16_bf16), p = exp2(S') UNSHIFTED (constant
//   shift cancels in O/l), O^T += V P^T (32x32x8; S^T C/D regs are B-frags).
//   8-wave partial (O,l) combine: 3-slot LDS tree + per-wave lsum array.
// ---------------------------------------------------------------------------

typedef __bf16 bf16x4 __attribute__((ext_vector_type(4)));
typedef __bf16 bf16x8 __attribute__((ext_vector_type(8)));
typedef float  f32x4  __attribute__((ext_vector_type(4)));
typedef float  f32x16 __attribute__((ext_vector_type(16)));
typedef short  s16x4  __attribute__((ext_vector_type(4)));

constexpr int C = 64;
constexpr int N = 4096;
constexpr float LOG2E = 1.44269504088896340736f;

static __device__ __forceinline__ f32x4 mfma16(bf16x8 a, bf16x8 b, f32x4 c) {
    return __builtin_amdgcn_mfma_f32_16x16x32_bf16(a, b, c, 0, 0, 0);
}
static __device__ __forceinline__ f32x16 mfma32(bf16x8 a, bf16x8 b, f32x16 c) {
    return __builtin_amdgcn_mfma_f32_32x32x16_bf16(a, b, c, 0, 0, 0);
}
// 32x32x8 bf16 (A/B = 4 bf16, k = 4*hi + j). Native if available, else
// zero-padded 32x32x16 (logical k at slot j in both operands).
static __device__ __forceinline__ f32x16 pv_mfma(bf16x4 a, bf16x4 b, f32x16 c) {
#if __has_builtin(__builtin_amdgcn_mfma_f32_32x32x8bf16_1k)
    union U { bf16x4 h; s16x4 s; };
    U ua; ua.h = a;
    U ub; ub.h = b;
    return __builtin_amdgcn_mfma_f32_32x32x8bf16_1k(ua.s, ub.s, c, 0, 0, 0);
#else
    const __bf16 z = (__bf16)0.0f;
    bf16x8 a8 = {a[0], a[1], a[2], a[3], z, z, z, z};
    bf16x8 b8 = {b[0], b[1], b[2], b[3], z, z, z, z};
    return __builtin_amdgcn_mfma_f32_32x32x16_bf16(a8, b8, c, 0, 0, 0);
#endif
}
static __device__ __forceinline__ float fast_exp2(float x) {
#if __has_builtin(__builtin_amdgcn_exp2f)
    return __builtin_amdgcn_exp2f(x);
#else
    return exp2f(x);
#endif
}

// ---------------------------------------------------------------------------
// QKV conv, 3-way split. grid = 768 x 256 thr. kind = bid>>8: 0=Q, 1=K, 2=V.
// Each block: one projection, 64 pixels, 4 waves x 16 pixels.
//   Q,K: D[n][o] = X^T W^T (A = x frag, B = W row-major from LDS)
//   V  : D[o][n] = W X     (A = W row-major from LDS, B = x frag)
// Results round-trip a padded LDS transpose so all global stores are 16B.
// ---------------------------------------------------------------------------
__global__ __launch_bounds__(256) void qkv_kernel(
    const float* __restrict__ x1, const float* __restrict__ x2,
    const float* __restrict__ wq, const float* __restrict__ bq,
    const float* __restrict__ wk, const float* __restrict__ bk,
    const float* __restrict__ wv, const float* __restrict__ bv,
    __bf16* __restrict__ qo, __bf16* __restrict__ ko, __bf16* __restrict__ vo)
{
    __shared__ __bf16 wl[64][72];     // W row-major, 9 KB
    __shared__ __bf16 tout[64][72];   // [pixel][o] transpose buffer, 9 KB

    const int bid  = blockIdx.x;
    const int kind = bid >> 8;                 // 0=Q, 1=K, 2=V (block-uniform)
    const int pg   = bid & 255;
    const int b     = pg >> 6;
    const int nbase = (pg & 63) * 64;
    const int tid   = threadIdx.x;

    const float* wsel = kind == 0 ? wq : (kind == 1 ? wk : wv);
    const float* bsel = kind == 0 ? bq : (kind == 1 ? bk : bv);
    const float* xsel = kind == 0 ? x1 : x2;
    __bf16*      osel = kind == 0 ? qo : (kind == 1 ? ko : vo);

    // ---- stage W (64x64 fp32 -> bf16 LDS) ----
#pragma unroll
    for (int i = 0; i < 4; ++i) {
        int idx = i * 256 + tid;
        int row = idx >> 4, c4 = (idx & 15) * 4;
        float4 a = *(const float4*)(wsel + row * 64 + c4);
        bf16x4 h = {(__bf16)a.x, (__bf16)a.y, (__bf16)a.z, (__bf16)a.w};
        *(bf16x4*)&wl[row][c4] = h;
    }
    __syncthreads();

    const int wave = tid >> 6, lane = tid & 63;
    const int l = lane & 15, qd = lane >> 4;
    const int p = nbase + wave * 16 + l;       // this lane's pixel

    // x fragment: A/B[k=c][pixel p], c = ks*32 + qd*8 + j
    const float* xb = xsel + (size_t)b * C * N + p;
    bf16x8 ax[2];
#pragma unroll
    for (int ks = 0; ks < 2; ++ks)
#pragma unroll
        for (int j = 0; j < 8; ++j)
            ax[ks][j] = (__bf16)xb[(size_t)(ks * 32 + qd * 8 + j) * N];

    if (kind < 2) {
        // ---- Q/K: D[pixel][o] ----
        const float scale = kind == 0 ? LOG2E : 1.0f;
#pragma unroll
        for (int ot = 0; ot < 4; ++ot) {
            const float bb = bsel[ot * 16 + l];
            f32x4 acc = {bb, bb, bb, bb};
#pragma unroll
            for (int ks = 0; ks < 2; ++ks) {
                bf16x8 bw = *(const bf16x8*)&wl[ot * 16 + l][ks * 32 + qd * 8];
                acc = mfma16(ax[ks], bw, acc);
            }
#pragma unroll
            for (int r = 0; r < 4; ++r) {
                int px = wave * 16 + qd * 4 + r;
                tout[px][ot * 16 + l] = (__bf16)(acc[r] * scale);
            }
        }
        __syncthreads();

        // ---- drain: frag-major 16B contiguous stores ----
        const int tile = tid >> 7, t7 = tid & 127;
        const int kc = t7 >> 5, h2 = (t7 >> 4) & 1, ilp = (t7 & 15) * 2;
        const size_t tb = ((size_t)b * 128 + (nbase >> 5) + tile) * 2048;
        const size_t off = tb + kc * 512 + h2 * 256 + ilp * 8;
        bf16x8 ra = *(const bf16x8*)&tout[tile * 32 + ilp][kc * 16 + h2 * 8];
        bf16x8 rb = *(const bf16x8*)&tout[tile * 32 + ilp + 1][kc * 16 + h2 * 8];
        *(bf16x8*)&osel[off]     = ra;
        *(bf16x8*)&osel[off + 8] = rb;
    } else {
        // ---- V: D[o][pixel] -> tout[pixel][o] ----
#pragma unroll
        for (int ct = 0; ct < 4; ++ct) {
            f32x4 acc;
#pragma unroll
            for (int r = 0; r < 4; ++r) acc[r] = bsel[ct * 16 + qd * 4 + r];
#pragma unroll
            for (int ks = 0; ks < 2; ++ks) {
                bf16x8 aw = *(const bf16x8*)&wl[ct * 16 + l][ks * 32 + qd * 8];
                acc = mfma16(aw, ax[ks], acc);
            }
            bf16x4 pk = {(__bf16)acc[0], (__bf16)acc[1], (__bf16)acc[2], (__bf16)acc[3]};
            *(bf16x4*)&tout[wave * 16 + l][ct * 16 + qd * 4] = pk;
        }
        __syncthreads();

        // ---- drain: [kcs][vhi][c][e4], 16B contiguous stores ----
        const int tile = tid >> 7, t7 = tid & 127;
        const int g = t7 >> 5, vh = (t7 >> 4) & 1, c0 = (t7 & 15) * 4;
        const int pxb = tile * 32 + g * 8 + vh * 4;
        bf16x4 e0 = *(const bf16x4*)&tout[pxb + 0][c0];
        bf16x4 e1 = *(const bf16x4*)&tout[pxb + 1][c0];
        bf16x4 e2 = *(const bf16x4*)&tout[pxb + 2][c0];
        bf16x4 e3 = *(const bf16x4*)&tout[pxb + 3][c0];
        bf16x8 o1, o2;
        o1[0]=e0[0]; o1[1]=e1[0]; o1[2]=e2[0]; o1[3]=e3[0];
        o1[4]=e0[1]; o1[5]=e1[1]; o1[6]=e2[1]; o1[7]=e3[1];
        o2[0]=e0[2]; o2[1]=e1[2]; o2[2]=e2[2]; o2[3]=e3[2];
        o2[4]=e0[3]; o2[5]=e1[3]; o2[6]=e2[3]; o2[7]=e3[3];
        const size_t tb = ((size_t)b * 128 + (nbase >> 5) + tile) * 2048;
        const size_t off = tb + g * 512 + vh * 256 + c0 * 4;
        *(bf16x8*)&osel[off]     = o1;
        *(bf16x8*)&osel[off + 8] = o2;
    }
}

// ---------------------------------------------------------------------------
// Attention (unchanged from round 9). grid = 256 blocks x 512 thr.
// Block = (b, 64-row Q-tile = 2 subtiles); wave w owns j-tiles [w*16,w*16+16).
// 32x32x16: A/B 8 elems k=(lane>>5)*8+j; C/D row=(r&3)+8*(r>>2)+4*hi, col=il.
// ---------------------------------------------------------------------------
__global__ __launch_bounds__(512, 2) void attn_kernel(
    const __bf16* __restrict__ qg, const __bf16* __restrict__ kg,
    const __bf16* __restrict__ vg, const float* __restrict__ x1,
    const float* __restrict__ gamma, float* __restrict__ out)
{
    __shared__ float lds_acc[3][64][64];   // 3 combine slots, 48 KB, [c][i]
    __shared__ float lds_l[8][64];         // per-wave lsum partials, [w][i]

    const int bid = blockIdx.x;
    const int xcd = bid & 7;
    const int b   = xcd >> 1;
    const int rt  = ((bid >> 3) << 1) | (xcd & 1);   // 0..63 (64-row tile)
    const int ibase = rt * 64;

    const int tid  = threadIdx.x;
    const int wave = tid >> 6, lane = tid & 63;
    const int il = lane & 31, hi = lane >> 5;

    const __bf16* qt = qg + ((size_t)b * 128 + rt * 2) * 2048;
    const __bf16* kt = kg + (size_t)b * 128 * 2048 + (size_t)(wave * 16) * 2048;
    const __bf16* vt = vg + (size_t)b * 128 * 2048 + (size_t)(wave * 16) * 2048;

    // Q B-frags for both 32-row subtiles: 1 KB contiguous per load
    bf16x8 bqf[2][4];
#pragma unroll
    for (int qs = 0; qs < 2; ++qs)
#pragma unroll
        for (int kc = 0; kc < 4; ++kc)
            bqf[qs][kc] = *(const bf16x8*)(qt + qs * 2048 + kc * 512 + lane * 8);

    f32x16 accO[4];   // [qs*2 + ct]
#pragma unroll
    for (int a = 0; a < 4; ++a)
#pragma unroll
        for (int r = 0; r < 16; ++r) accO[a][r] = 0.f;
    float lsum[2] = {0.f, 0.f};

    bf16x8 akf[2][4];   // K frags, double-buffered
    bf16x4 avf[2][4];   // V frags [ct][kcs]

#pragma unroll
    for (int kc = 0; kc < 4; ++kc)
        akf[0][kc] = *(const bf16x8*)(kt + kc * 512 + lane * 8);

#pragma unroll 2
    for (int t = 0; t < 16; ++t) {
        const int cur = t & 1;
        if (t < 15) {
#pragma unroll
            for (int kc = 0; kc < 4; ++kc)
                akf[cur ^ 1][kc] = *(const bf16x8*)(kt + (size_t)(t + 1) * 2048 + kc * 512 + lane * 8);
        }
#pragma unroll
        for (int ct = 0; ct < 2; ++ct)
#pragma unroll
            for (int kcs = 0; kcs < 4; ++kcs)
                avf[ct][kcs] = *(const bf16x4*)(vt + (size_t)t * 2048 + kcs * 512 + hi * 256 + ct * 128 + il * 4);

#pragma unroll
        for (int qs = 0; qs < 2; ++qs) {
            // S^T = K Q^T for this Q-subtile
            f32x16 st;
#pragma unroll
            for (int r = 0; r < 16; ++r) st[r] = 0.f;
#pragma unroll
            for (int kc = 0; kc < 4; ++kc) st = mfma32(akf[cur][kc], bqf[qs][kc], st);

            // p = exp2(S') (no shift; constant cancels in O/l).
            // regs 4g..4g+3 = B-frag of PV k-chunk g.
            bf16x4 bp[4];
            float lp0 = 0.f, lp1 = 0.f, lp2 = 0.f, lp3 = 0.f;
#pragma unroll
            for (int g = 0; g < 4; ++g) {
                float p0 = fast_exp2(st[g * 4 + 0]);
                float p1 = fast_exp2(st[g * 4 + 1]);
                float p2 = fast_exp2(st[g * 4 + 2]);
                float p3 = fast_exp2(st[g * 4 + 3]);
                lp0 += p0; lp1 += p1; lp2 += p2; lp3 += p3;
                bp[g][0] = (__bf16)p0; bp[g][1] = (__bf16)p1;
                bp[g][2] = (__bf16)p2; bp[g][3] = (__bf16)p3;
            }
            lsum[qs] += (lp0 + lp1) + (lp2 + lp3);

            // O^T += V P^T
#pragma unroll
            for (int ct = 0; ct < 2; ++ct)
#pragma unroll
                for (int g = 0; g < 4; ++g)
                    accO[qs * 2 + ct] = pv_mfma(avf[ct][g], bp[g], accO[qs * 2 + ct]);
        }
    }

    // per-lane lsum -> per-column(i) sum within wave (pair hi halves)
#pragma unroll
    for (int qs = 0; qs < 2; ++qs) lsum[qs] += __shfl_xor(lsum[qs], 32);
    if (hi == 0) {
        lds_l[wave][il]      = lsum[0];
        lds_l[wave][32 + il] = lsum[1];
    }

    // ---- cross-wave combine: 3-slot LDS tree ----
    // accO element (qs,ct,r) -> c = ct*32+(r&3)+8*(r>>2)+4*hi, i = qs*32+il
#define ACC_STORE(SLOT)                                                        \
    do {                                                                       \
        _Pragma("unroll")                                                      \
        for (int qs = 0; qs < 2; ++qs)                                         \
            _Pragma("unroll")                                                  \
            for (int ct = 0; ct < 2; ++ct)                                     \
                _Pragma("unroll")                                              \
                for (int r = 0; r < 16; ++r)                                   \
                    lds_acc[SLOT][ct * 32 + (r & 3) + 8 * (r >> 2) + 4 * hi][qs * 32 + il] = accO[qs * 2 + ct][r]; \
    } while (0)
#define ACC_LOAD(SLOT)                                                         \
    do {                                                                       \
        _Pragma("unroll")                                                      \
        for (int qs = 0; qs < 2; ++qs)                                         \
            _Pragma("unroll")                                                  \
            for (int ct = 0; ct < 2; ++ct)                                     \
                _Pragma("unroll")                                              \
                for (int r = 0; r < 16; ++r)                                   \
                    accO[qs * 2 + ct][r] += lds_acc[SLOT][ct * 32 + (r & 3) + 8 * (r >> 2) + 4 * hi][qs * 32 + il]; \
    } while (0)

    if (wave >= 5) ACC_STORE(wave - 5);                 // w5->0, w6->1, w7->2
    __syncthreads();
    if (wave >= 1 && wave <= 3) ACC_LOAD(wave - 1);     // w1+=w5, w2+=w6, w3+=w7
    __syncthreads();
    if (wave >= 2 && wave <= 4) ACC_STORE(wave - 2);    // w2->0, w3->1, w4->2
    __syncthreads();
    if (wave <= 1) ACC_LOAD(wave);                      // w0+=(w2+w6), w1+=(w3+w7)
    if (wave == 0) ACC_LOAD(2);                         // w0+=w4
    __syncthreads();
    if (wave == 1) ACC_STORE(0);                        // (w1+w5+w3+w7) -> s0
    __syncthreads();
    if (wave == 0) { ACC_LOAD(0); ACC_STORE(0); }       // total -> s0
    __syncthreads();
#undef ACC_STORE
#undef ACC_LOAD

    // ---- epilogue: out = gamma*O/l + x1 ----
    const float g = gamma[0];
    {
        const int c  = tid >> 3;           // 0..63
        const int i8 = (tid & 7) * 8;      // 0..56
        float lv[8];
#pragma unroll
        for (int e = 0; e < 8; ++e) {
            float s = 0.f;
#pragma unroll
            for (int w = 0; w < 8; ++w) s += lds_l[w][i8 + e];
            lv[e] = s;
        }
        const size_t idx = ((size_t)b * C + c) * N + ibase + i8;
        f32x4 o0 = *(const f32x4*)&lds_acc[0][c][i8];
        f32x4 o1 = *(const f32x4*)&lds_acc[0][c][i8 + 4];
        f32x4 x0 = *(const f32x4*)(x1 + idx);
        f32x4 x4 = *(const f32x4*)(x1 + idx + 4);
        f32x4 r0, r1;
#pragma unroll
        for (int e = 0; e < 4; ++e) {
            r0[e] = g * o0[e] / lv[e] + x0[e];
            r1[e] = g * o1[e] / lv[4 + e] + x4[e];
        }
        *(f32x4*)(out + idx) = r0;
        *(f32x4*)(out + idx + 4) = r1;
    }
}

// ---------------------------------------------------------------------------
extern "C" void kernel_launch(void* const* d_in, const int* in_sizes, int n_in,
                              void* d_out, int out_size, void* d_ws, size_t ws_size,
                              hipStream_t stream) {
    const float* x1    = (const float*)d_in[0];
    const float* x2    = (const float*)d_in[1];
    const float* wq    = (const float*)d_in[2];
    const float* bqv   = (const float*)d_in[3];
    const float* wk    = (const float*)d_in[4];
    const float* bkv   = (const float*)d_in[5];
    const float* wv    = (const float*)d_in[6];
    const float* bvv   = (const float*)d_in[7];
    const float* gamma = (const float*)d_in[8];
    float* out = (float*)d_out;

    __bf16* qws = (__bf16*)d_ws;                   // tiled Q, 2 MB
    __bf16* kws = qws + (size_t)4 * 128 * 2048;    // tiled K, 2 MB
    __bf16* vws = kws + (size_t)4 * 128 * 2048;    // tiled V, 2 MB

    qkv_kernel<<<768, 256, 0, stream>>>(x1, x2, wq, bqv, wk, bkv, wv, bvv, qws, kws, vws);
    attn_kernel<<<256, 512, 0, stream>>>(qws, kws, vws, x1, gamma, out);
}